// Round 11
// baseline (126.040 us; speedup 1.0000x reference)
//
#include <hip/hip_runtime.h>
#include <hip/hip_bf16.h>

#define NTOT   8192
#define BHALF  4096
#define DDIM   256
#define NPART  4
#define EXPSCALE 14.4269504088896341f   // 10 / ln(2): exp(10x) = exp2(EXPSCALE*x)

typedef __attribute__((ext_vector_type(8))) short bf16x8_t;  // 8 bf16 = 4 VGPRs
typedef __attribute__((ext_vector_type(4))) float f32x4_t;   // MFMA C/D

__device__ inline unsigned short f2bf(float x) {
    __hip_bfloat16 h = __float2bfloat16(x);
    return __builtin_bit_cast(unsigned short, h);
}

// ---- kernel 1: normalize pair k (rows k, k+B) -> bf16 zn; posdot; zero s_part ----
__global__ void norm_pair_kernel(const float* __restrict__ zi,
                                 const float* __restrict__ zj,
                                 unsigned short* __restrict__ zn,
                                 float* __restrict__ posdot,
                                 float* __restrict__ s_part) {
    int gtid = blockIdx.x * 256 + threadIdx.x;
    if (gtid < NTOT * NPART) s_part[gtid] = 0.0f;   // done before gemm (stream order)
    int k    = gtid >> 6;
    int lane = gtid & 63;
    float4 vi = reinterpret_cast<const float4*>(zi + (size_t)k * DDIM)[lane];
    float4 vj = reinterpret_cast<const float4*>(zj + (size_t)k * DDIM)[lane];
    float ssi = vi.x*vi.x + vi.y*vi.y + vi.z*vi.z + vi.w*vi.w;
    float ssj = vj.x*vj.x + vj.y*vj.y + vj.z*vj.z + vj.w*vj.w;
    float dot = vi.x*vj.x + vi.y*vj.y + vi.z*vj.z + vi.w*vj.w;
    #pragma unroll
    for (int off = 32; off >= 1; off >>= 1) {
        ssi += __shfl_xor(ssi, off);
        ssj += __shfl_xor(ssj, off);
        dot += __shfl_xor(dot, off);
    }
    float ri = 1.0f / fmaxf(sqrtf(ssi), 1e-8f);
    float rj = 1.0f / fmaxf(sqrtf(ssj), 1e-8f);
    ushort4 oi, oj;
    oi.x = f2bf(vi.x * ri); oi.y = f2bf(vi.y * ri);
    oi.z = f2bf(vi.z * ri); oi.w = f2bf(vi.w * ri);
    oj.x = f2bf(vj.x * rj); oj.y = f2bf(vj.y * rj);
    oj.z = f2bf(vj.z * rj); oj.w = f2bf(vj.w * rj);
    reinterpret_cast<ushort4*>(zn + (size_t)k * DDIM)[lane] = oi;
    reinterpret_cast<ushort4*>(zn + (size_t)(k + BHALF) * DDIM)[lane] = oj;
    if (lane == 0) posdot[k] = dot * ri * rj * 10.0f;
}

// ---- kernel 2: full-matrix fused GEMM + row exp-sum, rf=4.
// Grid (32,16): block = 256 rows x 512 cols (8 strips of 64 cols).
// Wave owns 64 rows: afrag[4][8] (128 VGPR, loaded once) -> each LDS B-read
// feeds 4 MFMAs, halving LDS reads/writes/barriers/staging-VALU per FLOP vs
// the rf=2 rounds (r2/r8/r10, all ~52-58 µs). B strips: r10's register
// prefetch + xor-swizzled LDS staging (verified). __launch_bounds__(256,1)
// lifts the VGPR cap (min-waves>=2 clamps to 64 and spills: r5/r7); ~210 VGPR
// -> 2 waves/SIMD, 2 blocks/CU resident.
__global__ void __launch_bounds__(256, 1)
gemm_kernel(const unsigned short* __restrict__ zn,
            float* __restrict__ s_part) {
    __shared__ unsigned short ldsB[64 * 256];   // 32 KB

    const int tid  = threadIdx.x;
    const int lane = tid & 63;
    const int wv   = tid >> 6;        // 0..3 -> 64-row slice
    const int m    = lane & 15;
    const int quad = lane >> 4;
    const int bi   = blockIdx.x;      // 0..31 row block (256 rows)
    const int s    = blockIdx.y;      // 0..15 col split (512 cols)
    const int R0   = bi << 8;
    const int CB   = s << 9;

    float* rowPart = s_part + (size_t)(s & (NPART - 1)) * NTOT;

    // A fragments: rows R0 + wv*64 + rf*16 + m, k = kk*32 + quad*8 (+j)
    bf16x8_t afrag[4][8];
    #pragma unroll
    for (int rf = 0; rf < 4; ++rf) {
        const unsigned short* arow = zn + (size_t)(R0 + wv*64 + rf*16 + m) * DDIM;
        #pragma unroll
        for (int kk = 0; kk < 8; ++kk)
            afrag[rf][kk] = *reinterpret_cast<const bf16x8_t*>(arow + kk*32 + quad*8);
    }

    // prefetch strip 0 into registers (8 x 16B chunks per thread)
    bf16x8_t pf[8];
    {
        const int c = tid & 31, r0 = tid >> 5;
        #pragma unroll
        for (int t = 0; t < 8; ++t)
            pf[t] = *reinterpret_cast<const bf16x8_t*>(
                        zn + (size_t)(CB + t*8 + r0) * DDIM + c * 8);
    }

    float rowacc[4][4] = {{0.f,0.f,0.f,0.f},{0.f,0.f,0.f,0.f},
                          {0.f,0.f,0.f,0.f},{0.f,0.f,0.f,0.f}};

    for (int it = 0; it < 8; ++it) {
        const int C0 = CB + it * 64;
        const bool isDiag = ((C0 >> 8) == bi);   // strip cols inside this row block?

        __syncthreads();   // previous strip's readers done
        // write prefetched strip: chunk c of row r -> slot (c ^ (r&7))
        {
            const int c = tid & 31, r0 = tid >> 5;
            #pragma unroll
            for (int t = 0; t < 8; ++t) {
                int r = t*8 + r0;
                *reinterpret_cast<bf16x8_t*>(&ldsB[r * 256 + ((c ^ (r & 7)) << 3)]) = pf[t];
            }
        }
        __syncthreads();   // staging visible

        // prefetch next strip (loads in flight across the whole compute phase)
        if (it < 7) {
            const int c = tid & 31, r0 = tid >> 5;
            #pragma unroll
            for (int t = 0; t < 8; ++t)
                pf[t] = *reinterpret_cast<const bf16x8_t*>(
                            zn + (size_t)(C0 + 64 + t*8 + r0) * DDIM + c * 8);
        }

        #pragma unroll
        for (int cf = 0; cf < 4; ++cf) {
            f32x4_t cacc[4];
            #pragma unroll
            for (int rf = 0; rf < 4; ++rf) cacc[rf] = (f32x4_t){0.f,0.f,0.f,0.f};
            #pragma unroll
            for (int kk = 0; kk < 8; ++kk) {
                bf16x8_t b = *reinterpret_cast<const bf16x8_t*>(
                    &ldsB[(cf*16 + m) * 256 + (((kk*4 + quad) ^ (m & 7)) << 3)]);
                #pragma unroll
                for (int rf = 0; rf < 4; ++rf)
                    cacc[rf] = __builtin_amdgcn_mfma_f32_16x16x32_bf16(
                        afrag[rf][kk], b, cacc[rf], 0, 0, 0);
            }
            const int gc = C0 + cf*16 + m;
            if (isDiag) {
                #pragma unroll
                for (int rf = 0; rf < 4; ++rf)
                    #pragma unroll
                    for (int r = 0; r < 4; ++r) {
                        int gr = R0 + wv*64 + rf*16 + quad*4 + r;
                        float e = exp2f(cacc[rf][r] * EXPSCALE);
                        rowacc[rf][r] += (gr == gc) ? 0.f : e;
                    }
            } else {
                #pragma unroll
                for (int rf = 0; rf < 4; ++rf)
                    #pragma unroll
                    for (int r = 0; r < 4; ++r)
                        rowacc[rf][r] += exp2f(cacc[rf][r] * EXPSCALE);
            }
        }
    }

    // row totals: reduce over 16 m-lanes sharing a row, one atomic per row
    #pragma unroll
    for (int rf = 0; rf < 4; ++rf)
        #pragma unroll
        for (int r = 0; r < 4; ++r) {
            float v = rowacc[rf][r];
            v += __shfl_xor(v, 1);
            v += __shfl_xor(v, 2);
            v += __shfl_xor(v, 4);
            v += __shfl_xor(v, 8);
            if (m == 0)
                atomicAdd(&rowPart[R0 + wv*64 + rf*16 + quad*4 + r], v);
        }
}

// ---- kernel 3: loss_k = log(sum_p s_part[p][k]) - posdot[k%B]; masked mean ----
__global__ void finalize_kernel(const float* __restrict__ s_part,
                                const float* __restrict__ posdot,
                                const unsigned char* __restrict__ mask,
                                float* __restrict__ out) {
    int tid = threadIdx.x, lane = tid & 63, wv = tid >> 6;
    float tot = 0.f, cnt = 0.f;
    #pragma unroll
    for (int si = 0; si < NTOT / 1024; ++si) {
        int k = si * 1024 + tid;
        int kb = k & (BHALF - 1);
        if (mask[kb] != 0) {
            float sk = s_part[k] + s_part[NTOT + k]
                     + s_part[2*NTOT + k] + s_part[3*NTOT + k];
            tot += __logf(sk) - posdot[kb];
            cnt += 1.f;
        }
    }
    #pragma unroll
    for (int off = 32; off >= 1; off >>= 1) {
        tot += __shfl_xor(tot, off);
        cnt += __shfl_xor(cnt, off);
    }
    __shared__ float st[16], sc[16];
    if (lane == 0) { st[wv] = tot; sc[wv] = cnt; }
    __syncthreads();
    if (tid == 0) {
        float T = 0.f, C = 0.f;
        #pragma unroll
        for (int i = 0; i < 16; ++i) { T += st[i]; C += sc[i]; }
        out[0] = (C > 0.f) ? (T / fmaxf(C, 1.f)) : 0.f;
    }
}

extern "C" void kernel_launch(void* const* d_in, const int* in_sizes, int n_in,
                              void* d_out, int out_size, void* d_ws, size_t ws_size,
                              hipStream_t stream) {
    const float* zi = (const float*)d_in[0];
    const float* zj = (const float*)d_in[1];
    const unsigned char* mask = (const unsigned char*)d_in[2];
    float* out = (float*)d_out;

    // ws: [0,4MB) zn bf16; s_part[NPART][8192] f32; posdot[4096] f32
    unsigned short* zn = (unsigned short*)d_ws;
    float* s_part = (float*)((char*)d_ws + (size_t)NTOT * DDIM * 2);
    float* posdot = s_part + NPART * NTOT;

    norm_pair_kernel<<<dim3(1024), dim3(256), 0, stream>>>(zi, zj, zn, posdot, s_part);
    gemm_kernel<<<dim3(32, 16), dim3(256), 0, stream>>>(zn, s_part);
    finalize_kernel<<<dim3(1), dim3(1024), 0, stream>>>(s_part, posdot, mask, out);
}